// Round 8
// baseline (276.636 us; speedup 1.0000x reference)
//
#include <hip/hip_runtime.h>

typedef _Float16 half8 __attribute__((ext_vector_type(8)));
typedef _Float16 half4 __attribute__((ext_vector_type(4)));
typedef float f32x4 __attribute__((ext_vector_type(4)));
typedef int int4v __attribute__((ext_vector_type(4)));

#define ROWS 32                 // 32 rows x 4 waves/block; 512 blocks = 2 independent blocks/CU
#define HP 136                  // h row pitch (halfs): 128 + 8 pad; 272 B
#define HBUFSZ (ROWS * HP)
#define LOG2E 1.442695041f
#define MFMA(a,b,c) __builtin_amdgcn_mfma_f32_16x16x32_f16((a),(b),(c),0,0,0)

// Mechanism (r0-r7 evidence): MFMA blocks its wave; block-wide barriers
// re-lock all waves into the same phase each step -> MfmaUtil+VALUBusy
// additive (~87%), zero pipe overlap. Fix: two barrier-INDEPENDENT blocks
// per CU (1 wave of each per SIMD); contention drives them to anti-phase,
// MFMA burst of one overlaps gates burst of the other. Per-wave stream is
// byte-identical to r7 (60 MFMA + 16 gate-elems / gru step).
__global__ __launch_bounds__(256, 2)   // 2 waves/EU -> VGPR cap 256 (r7 used 128)
void traj_gru(const float* __restrict__ history,
              const float* __restrict__ w_ih, const float* __restrict__ w_hh,
              const float* __restrict__ b_ih, const float* __restrict__ b_hh,
              const float* __restrict__ w1, const float* __restrict__ b1,
              const float* __restrict__ w2, const float* __restrict__ b2,
              float* __restrict__ out)
{
    __shared__ __align__(16) _Float16 hbuf[2 * HBUFSZ];     // 17,408 B; a1 aliases dead half
    __shared__ __align__(16) _Float16 xhist[50 * ROWS * 6]; // 19,200 B compact [t][row][6]
    __shared__ __align__(16) _Float16 xdec[ROWS * 8];       //    512 B
    __shared__ __align__(16) _Float16 w2f[4 * 4 * 16 * 8];  //  4,096 B
    __shared__ __align__(16) _Float16 w1f[4 * 4 * 128 * 8]; // 32,768 B => 73,984 total; x2 = 148KB/CU

    const int tid  = threadIdx.x;
    const int wave = tid >> 6;               // 0..3
    const int lane = tid & 63;
    const int ln16 = lane & 15;
    const int q    = lane >> 4;
    const int dg   = wave;                   // dim group: dims dg*32 .. dg*32+31
    const int rowbase = blockIdx.x * ROWS;

    // ---- init LDS: zeros first, barrier, then fills ----
    for (int i = tid; i < 2 * HBUFSZ; i += 256) hbuf[i] = (_Float16)0;
    for (int i = tid; i < ROWS * 8; i += 256) xdec[i] = (_Float16)0;
    for (int i = tid; i < 4 * 4 * 16 * 8; i += 256) w2f[i] = (_Float16)0;
    __syncthreads();
    for (int idx = tid; idx < ROWS * 300; idx += 256) {
        int r = idx / 300, rem = idx - r * 300;
        int t = rem / 6, c = rem - t * 6;
        xhist[(t * ROWS + r) * 6 + c] = (_Float16)history[(rowbase + r) * 300 + rem];
    }
    if (tid < ROWS) xdec[tid * 8 + 6] = (_Float16)1.0f;   // decoder bias slot
    for (int idx = tid; idx < 6 * 128; idx += 256) {      // w2 -> B-frag layout
        int n = idx >> 7, k = idx & 127;
        int kt = k >> 5, qq = (k >> 3) & 3, j = k & 7;
        w2f[((kt * 4 + qq) * 16 + n) * 8 + j] = (_Float16)w2[n * 128 + k];
    }
    for (int idx = tid; idx < 16384; idx += 256) {        // w1 -> B-frag layout in LDS
        int j = idx & 7, d = (idx >> 3) & 127, fq = idx >> 10;
        int kt = fq >> 2, qq = fq & 3;
        w1f[idx] = (_Float16)w1[d * 128 + kt * 32 + qq * 8 + j];
    }

    // ---- persistent register fragments (as r7, bh removed) ----
    half8 Wg[3][4][2];
    #pragma unroll
    for (int g = 0; g < 3; ++g) {
        float sc = (g < 2) ? -LOG2E : -2.0f * LOG2E;
        #pragma unroll
        for (int mt = 0; mt < 2; ++mt) {
            #pragma unroll
            for (int kt = 0; kt < 4; ++kt) {
                const float* p = w_hh + (g * 128 + dg * 32 + mt * 16 + ln16) * 128 + kt * 32 + q * 8;
                half8 v;
                #pragma unroll
                for (int j = 0; j < 8; ++j) v[j] = (_Float16)(p[j] * sc);
                Wg[g][kt][mt] = v;
            }
        }
    }
    half8 Wx[3][2];      // x-weights + bias in slot 6 (rides x-vector's 1.0)
    #pragma unroll
    for (int g = 0; g < 3; ++g) {
        float sc = (g < 2) ? -LOG2E : -2.0f * LOG2E;
        #pragma unroll
        for (int mt = 0; mt < 2; ++mt) {
            half8 v;
            #pragma unroll
            for (int j = 0; j < 8; ++j) v[j] = (_Float16)0.0f;
            if (q == 0) {
                int d = dg * 32 + mt * 16 + ln16;
                #pragma unroll
                for (int j = 0; j < 6; ++j) v[j] = (_Float16)(w_ih[(g * 128 + d) * 6 + j] * sc);
                float bias;
                if      (g == 0) bias = b_ih[d]       + b_hh[d];
                else if (g == 1) bias = b_ih[128 + d] + b_hh[128 + d];
                else             bias = b_ih[256 + d];
                v[6] = (_Float16)(bias * sc);
            }
            Wx[g][mt] = v;
        }
    }
    f32x4 bhn[2];
    #pragma unroll
    for (int mt = 0; mt < 2; ++mt)
        #pragma unroll
        for (int i = 0; i < 4; ++i)
            bhn[mt][i] = b_hh[256 + dg * 32 + mt * 16 + q * 4 + i] * (-2.0f * LOG2E);

    float b1rv[2];
    b1rv[0] = b1[dg * 32 + ln16];
    b1rv[1] = b1[dg * 32 + 16 + ln16];
    const float b2r = (ln16 < 6) ? b2[ln16] : 0.0f;

    float hp[2][2][4] = {};  // [c2][mt][i]: (batch=c2*16+ln16, dim=dg*32+mt*16+q*4+i)

    __syncthreads();

    // Seed anti-phase between the 2 co-resident blocks (pairing guess: b and
    // b+256 share a CU). ~2.4k cyc ~= half a step. Harmless if pairing wrong.
    if ((blockIdx.x >> 8) & 1) __builtin_amdgcn_s_sleep(38);

    // ---- GRU step: 2 chunks x 2 m-tiles per wave ----
    auto gru_step = [&](int p, int t, bool enc) {
        const _Float16* hb = hbuf + p * HBUFSZ;
        _Float16*       hn = hbuf + (p ^ 1) * HBUFSZ;
        half8 Bf[2][4], Bx[2];

        auto loadB = [&](int c2) {
            const _Float16* rp = hb + (c2 * 16 + ln16) * HP;
            #pragma unroll
            for (int kt = 0; kt < 4; ++kt)
                Bf[c2][kt] = *(const half8*)(rp + kt * 32 + q * 8);
            if (enc) {
                const int* xi = (const int*)xhist;
                int base = (t * ROWS + c2 * 16 + ln16) * 3;
                int4v dv = { xi[base], xi[base + 1], xi[base + 2], 0x3C00 };
                Bx[c2] = __builtin_bit_cast(half8, dv);
            } else {
                Bx[c2] = *(const half8*)(xdec + (c2 * 16 + ln16) * 8);
            }
        };
        auto mfmas = [&](int c2, f32x4 (&A)[2][4]) {
            #pragma unroll
            for (int mt = 0; mt < 2; ++mt) {
                f32x4 r = {0,0,0,0}, z = {0,0,0,0}, n = {0,0,0,0}, hh = bhn[mt];
                #pragma unroll
                for (int kt = 0; kt < 4; ++kt) {
                    r  = MFMA(Wg[0][kt][mt], Bf[c2][kt], r);
                    z  = MFMA(Wg[1][kt][mt], Bf[c2][kt], z);
                    hh = MFMA(Wg[2][kt][mt], Bf[c2][kt], hh);
                }
                r = MFMA(Wx[0][mt], Bx[c2], r);
                z = MFMA(Wx[1][mt], Bx[c2], z);
                n = MFMA(Wx[2][mt], Bx[c2], n);
                A[mt][0] = r; A[mt][1] = z; A[mt][2] = hh; A[mt][3] = n;
            }
        };
        auto gates = [&](int c2, f32x4 (&A)[2][4]) {
            #pragma unroll
            for (int mt = 0; mt < 2; ++mt) {
                half4 hv;
                #pragma unroll
                for (int i = 0; i < 4; ++i) {
                    float rr = __builtin_amdgcn_rcpf(1.0f + __builtin_amdgcn_exp2f(A[mt][0][i]));
                    float zz = __builtin_amdgcn_rcpf(1.0f + __builtin_amdgcn_exp2f(A[mt][1][i]));
                    float tt = A[mt][3][i] + rr * A[mt][2][i];
                    float nn = 2.0f * __builtin_amdgcn_rcpf(1.0f + __builtin_amdgcn_exp2f(tt)) - 1.0f;
                    float h = nn + zz * (hp[c2][mt][i] - nn);
                    hp[c2][mt][i] = h;
                    hv[i] = (_Float16)h;
                }
                *(half4*)(hn + (c2 * 16 + ln16) * HP + dg * 32 + mt * 16 + q * 4) = hv;
            }
        };

        f32x4 accA[2][4], accB[2][4];
        loadB(0);
        mfmas(0, accA);
        loadB(1);
        gates(0, accA);
        mfmas(1, accB);
        gates(1, accB);
        __syncthreads();
    };

    // ---- head step: phase1 per-wave dim-split; phase2 waves 0-1 ----
    auto head_step = [&](int f, int p) {
        const _Float16* hb = hbuf + p * HBUFSZ;
        _Float16*       a1s = hbuf + (p ^ 1) * HBUFSZ;   // dead ping-pong half
        half8 Bw[4][2];
        #pragma unroll
        for (int kt = 0; kt < 4; ++kt)
            #pragma unroll
            for (int nt = 0; nt < 2; ++nt)
                Bw[kt][nt] = *(const half8*)(w1f + ((kt * 4 + q) * 128 + dg * 32 + nt * 16 + ln16) * 8);
        #pragma unroll
        for (int c2 = 0; c2 < 2; ++c2) {
            const _Float16* rp = hb + (c2 * 16 + ln16) * HP;
            half8 Ah[4];
            #pragma unroll
            for (int kt = 0; kt < 4; ++kt)
                Ah[kt] = *(const half8*)(rp + kt * 32 + q * 8);
            f32x4 a0 = {0,0,0,0}, a1v = {0,0,0,0};
            #pragma unroll
            for (int kt = 0; kt < 4; ++kt) {
                a0  = MFMA(Ah[kt], Bw[kt][0], a0);
                a1v = MFMA(Ah[kt], Bw[kt][1], a1v);
            }
            // stored col[6:5] = dg ^ (row&3); dim[4]=nt (verified swizzle pair)
            #pragma unroll
            for (int i = 0; i < 4; ++i) {
                float v0 = a0[i] + b1rv[0];
                v0 = v0 > 0.0f ? v0 : 0.0f;
                a1s[(c2 * 16 + q * 4 + i) * HP + ((dg ^ i) << 5) + ln16] = (_Float16)v0;
                float v1 = a1v[i] + b1rv[1];
                v1 = v1 > 0.0f ? v1 : 0.0f;
                a1s[(c2 * 16 + q * 4 + i) * HP + ((dg ^ i) << 5) + 16 + ln16] = (_Float16)v1;
            }
        }
        __syncthreads();
        if (wave < 2) {   // phase 2: A=a1 (m=batch rows wave*16..), B=w2f
            const int sw = ln16 & 3;
            const _Float16* rp = a1s + (wave * 16 + ln16) * HP;
            f32x4 o = {0,0,0,0};
            #pragma unroll
            for (int kt = 0; kt < 4; ++kt) {
                half8 Aa = *(const half8*)(rp + ((kt ^ sw) << 5) + q * 8);
                half8 Bw2 = *(const half8*)&w2f[((kt * 4 + q) * 16 + ln16) * 8];
                o = MFMA(Aa, Bw2, o);
            }
            if (ln16 < 6) {
                #pragma unroll
                for (int i = 0; i < 4; ++i) {
                    int row = wave * 16 + q * 4 + i;
                    float v = o[i] + b2r;
                    out[(rowbase + row) * 180 + f * 6 + ln16] = v;
                    xdec[row * 8 + ln16] = (_Float16)v;   // next decoder x
                }
            }
        }
        __syncthreads();
    };

    int p = 0;
    #pragma unroll 1
    for (int t = 0; t < 50; ++t) { gru_step(p, t, true); p ^= 1; }
    #pragma unroll 1
    for (int f = 0; f < 30; ++f) {
        gru_step(p, f == 0 ? 49 : 0, f == 0);   // f=0: x = history[:,49]
        p ^= 1;
        head_step(f, p);
    }
}

extern "C" void kernel_launch(void* const* d_in, const int* in_sizes, int n_in,
                              void* d_out, int out_size, void* d_ws, size_t ws_size,
                              hipStream_t stream) {
    (void)in_sizes; (void)n_in; (void)d_ws; (void)ws_size; (void)out_size;
    traj_gru<<<dim3(16384 / ROWS), dim3(256), 0, stream>>>(
        (const float*)d_in[0], (const float*)d_in[1], (const float*)d_in[2],
        (const float*)d_in[3], (const float*)d_in[4], (const float*)d_in[5],
        (const float*)d_in[6], (const float*)d_in[7], (const float*)d_in[8],
        (float*)d_out);
}

// Round 10
// 272.402 us; speedup vs baseline: 1.0155x; 1.0155x over previous
//
#include <hip/hip_runtime.h>

typedef _Float16 half8 __attribute__((ext_vector_type(8)));
typedef _Float16 half4 __attribute__((ext_vector_type(4)));
typedef float f32x4 __attribute__((ext_vector_type(4)));
typedef int int4v __attribute__((ext_vector_type(4)));

#define ROWS 64
#define HP 136                  // h row pitch (halfs): 128 + 8 pad; 272 B
#define HBUFSZ (ROWS * HP)
#define LOG2E 1.442695041f
#define MFMA(a,b,c) __builtin_amdgcn_mfma_f32_16x16x32_f16((a),(b),(c),0,0,0)

// Verified best (r7, 232.9us). Issue-port model (r5/r6/r8 structural nulls):
// SIMD has ONE shared issue port; MfmaUtil+VALUBusy ~87% = issue occupancy.
// This decomposition is MFMA-count-minimal for 16x16x32 (480 tiles/CU/step,
// zero replication); trans ops irreducible; 32x32 loses to reg pressure (r9);
// fp8 can't hold 4e-3 absmax over 80 recurrent steps. This is the floor.
__global__ __launch_bounds__(512, 2)
void traj_gru(const float* __restrict__ history,
              const float* __restrict__ w_ih, const float* __restrict__ w_hh,
              const float* __restrict__ b_ih, const float* __restrict__ b_hh,
              const float* __restrict__ w1, const float* __restrict__ b1,
              const float* __restrict__ w2, const float* __restrict__ b2,
              float* __restrict__ out)
{
    __shared__ __align__(16) _Float16 hbuf[2 * HBUFSZ];     // 34,816 B; a1 aliases dead half
    __shared__ __align__(16) _Float16 xhist[50 * ROWS * 6]; // 38,400 B compact [t][row][6]
    __shared__ __align__(16) _Float16 xdec[ROWS * 8];       //  1,024 B
    __shared__ __align__(16) _Float16 w2f[4 * 4 * 16 * 8];  //  4,096 B
    __shared__ __align__(16) _Float16 w1f[4 * 4 * 128 * 8]; // 32,768 B => 111,104 total

    const int tid  = threadIdx.x;
    const int wave = tid >> 6;
    const int lane = tid & 63;
    const int ln16 = lane & 15;
    const int q    = lane >> 4;
    const int bh   = wave >> 2;              // batch half: chunks {2bh, 2bh+1}
    const int dg   = wave & 3;               // dim group: dims dg*32 .. dg*32+31
    const int rowbase = blockIdx.x * ROWS;

    // ---- init LDS: zeros first, barrier, then fills ----
    for (int i = tid; i < 2 * HBUFSZ; i += 512) hbuf[i] = (_Float16)0;
    for (int i = tid; i < ROWS * 8; i += 512) xdec[i] = (_Float16)0;
    for (int i = tid; i < 4 * 4 * 16 * 8; i += 512) w2f[i] = (_Float16)0;
    __syncthreads();
    for (int idx = tid; idx < ROWS * 300; idx += 512) {
        int r = idx / 300, rem = idx - r * 300;
        int t = rem / 6, c = rem - t * 6;
        xhist[(t * ROWS + r) * 6 + c] = (_Float16)history[(rowbase + r) * 300 + rem];
    }
    if (tid < ROWS) xdec[tid * 8 + 6] = (_Float16)1.0f;   // decoder bias slot
    for (int idx = tid; idx < 6 * 128; idx += 512) {      // w2 -> B-frag layout
        int n = idx >> 7, k = idx & 127;
        int kt = k >> 5, qq = (k >> 3) & 3, j = k & 7;
        w2f[((kt * 4 + qq) * 16 + n) * 8 + j] = (_Float16)w2[n * 128 + k];
    }
    for (int idx = tid; idx < 16384; idx += 512) {        // w1 -> B-frag layout in LDS
        int j = idx & 7, d = (idx >> 3) & 127, fq = idx >> 10;
        int kt = fq >> 2, qq = fq & 3;
        w1f[idx] = (_Float16)w1[d * 128 + kt * 32 + qq * 8 + j];  // layout == idx
    }

    // ---- persistent register fragments ----
    // GRU (transposed): A-side weights, m=ln16 -> dim dg*32+mt*16+ln16,
    // k=kt*32+q*8+j. r,z scaled -log2e; n by -2log2e.
    half8 Wg[3][4][2];
    #pragma unroll
    for (int g = 0; g < 3; ++g) {
        float sc = (g < 2) ? -LOG2E : -2.0f * LOG2E;
        #pragma unroll
        for (int mt = 0; mt < 2; ++mt) {
            #pragma unroll
            for (int kt = 0; kt < 4; ++kt) {
                const float* p = w_hh + (g * 128 + dg * 32 + mt * 16 + ln16) * 128 + kt * 32 + q * 8;
                half8 v;
                #pragma unroll
                for (int j = 0; j < 8; ++j) v[j] = (_Float16)(p[j] * sc);
                Wg[g][kt][mt] = v;
            }
        }
    }
    // Wx: x-weights + (for r,z,n) bias in slot 6 (multiplies the x-vector 1.0)
    half8 Wx[3][2];
    #pragma unroll
    for (int g = 0; g < 3; ++g) {
        float sc = (g < 2) ? -LOG2E : -2.0f * LOG2E;
        #pragma unroll
        for (int mt = 0; mt < 2; ++mt) {
            half8 v;
            #pragma unroll
            for (int j = 0; j < 8; ++j) v[j] = (_Float16)0.0f;
            if (q == 0) {
                int d = dg * 32 + mt * 16 + ln16;
                #pragma unroll
                for (int j = 0; j < 6; ++j) v[j] = (_Float16)(w_ih[(g * 128 + d) * 6 + j] * sc);
                float bias;
                if      (g == 0) bias = b_ih[d]       + b_hh[d];
                else if (g == 1) bias = b_ih[128 + d] + b_hh[128 + d];
                else             bias = b_ih[256 + d];
                v[6] = (_Float16)(bias * sc);
            }
            Wx[g][mt] = v;
        }
    }
    // hh-acc init: b_hh n-part (C-layout: row = dim dg*32+mt*16+q*4+i)
    f32x4 bhn[2];
    #pragma unroll
    for (int mt = 0; mt < 2; ++mt)
        #pragma unroll
        for (int i = 0; i < 4; ++i)
            bhn[mt][i] = b_hh[256 + dg * 32 + mt * 16 + q * 4 + i] * (-2.0f * LOG2E);

    float b1rv[2];
    b1rv[0] = b1[dg * 32 + ln16];
    b1rv[1] = b1[dg * 32 + 16 + ln16];
    const float b2r = (ln16 < 6) ? b2[ln16] : 0.0f;

    float hp[2][2][4] = {};  // [c2][mt][i]: (batch=(2bh+c2)*16+ln16, dim=dg*32+mt*16+q*4+i)

    __syncthreads();

    // ---- GRU step: 2 chunks x 2 m-tiles per wave ----
    auto gru_step = [&](int p, int t, bool enc) {
        const _Float16* hb = hbuf + p * HBUFSZ;
        _Float16*       hn = hbuf + (p ^ 1) * HBUFSZ;
        half8 Bf[2][4], Bx[2];

        auto loadB = [&](int c2) {
            int c = 2 * bh + c2;
            const _Float16* rp = hb + (c * 16 + ln16) * HP;
            #pragma unroll
            for (int kt = 0; kt < 4; ++kt)
                Bf[c2][kt] = *(const half8*)(rp + kt * 32 + q * 8);
            if (enc) {   // compact [t][row][6] + [1.0, 0] packed in regs
                const int* xi = (const int*)xhist;
                int base = (t * ROWS + c * 16 + ln16) * 3;
                int4v dv = { xi[base], xi[base + 1], xi[base + 2], 0x3C00 };
                Bx[c2] = __builtin_bit_cast(half8, dv);
            } else {
                Bx[c2] = *(const half8*)(xdec + (c * 16 + ln16) * 8);
            }
        };
        auto mfmas = [&](int c2, f32x4 (&A)[2][4]) {
            #pragma unroll
            for (int mt = 0; mt < 2; ++mt) {
                f32x4 r = {0,0,0,0}, z = {0,0,0,0}, n = {0,0,0,0}, hh = bhn[mt];
                #pragma unroll
                for (int kt = 0; kt < 4; ++kt) {
                    r  = MFMA(Wg[0][kt][mt], Bf[c2][kt], r);
                    z  = MFMA(Wg[1][kt][mt], Bf[c2][kt], z);
                    hh = MFMA(Wg[2][kt][mt], Bf[c2][kt], hh);
                }
                r = MFMA(Wx[0][mt], Bx[c2], r);   // slot6 carries (b_ih+b_hh) r-bias
                z = MFMA(Wx[1][mt], Bx[c2], z);
                n = MFMA(Wx[2][mt], Bx[c2], n);   // slot6 carries b_ih n-bias
                A[mt][0] = r; A[mt][1] = z; A[mt][2] = hh; A[mt][3] = n;
            }
        };
        auto gates = [&](int c2, f32x4 (&A)[2][4]) {
            int c = 2 * bh + c2;
            #pragma unroll
            for (int mt = 0; mt < 2; ++mt) {
                half4 hv;
                #pragma unroll
                for (int i = 0; i < 4; ++i) {
                    float rr = __builtin_amdgcn_rcpf(1.0f + __builtin_amdgcn_exp2f(A[mt][0][i]));
                    float zz = __builtin_amdgcn_rcpf(1.0f + __builtin_amdgcn_exp2f(A[mt][1][i]));
                    float tt = A[mt][3][i] + rr * A[mt][2][i];
                    float nn = 2.0f * __builtin_amdgcn_rcpf(1.0f + __builtin_amdgcn_exp2f(tt)) - 1.0f;
                    float h = nn + zz * (hp[c2][mt][i] - nn);
                    hp[c2][mt][i] = h;
                    hv[i] = (_Float16)h;
                }
                *(half4*)(hn + (c * 16 + ln16) * HP + dg * 32 + mt * 16 + q * 4) = hv;
            }
        };

        f32x4 accA[2][4], accB[2][4];
        loadB(0);
        mfmas(0, accA);
        loadB(1);            // issue chunk-1 LDS reads under chunk-0 gates
        gates(0, accA);
        mfmas(1, accB);
        gates(1, accB);
        __syncthreads();
    };

    // ---- head step: phase1 batch-split (w1 frags from LDS); phase2 as r0 ----
    auto head_step = [&](int f, int p) {
        const _Float16* hb = hbuf + p * HBUFSZ;
        _Float16*       a1s = hbuf + (p ^ 1) * HBUFSZ;   // dead ping-pong half
        half8 Bw[4][2];
        #pragma unroll
        for (int kt = 0; kt < 4; ++kt)
            #pragma unroll
            for (int nt = 0; nt < 2; ++nt)
                Bw[kt][nt] = *(const half8*)(w1f + ((kt * 4 + q) * 128 + dg * 32 + nt * 16 + ln16) * 8);
        #pragma unroll
        for (int c2 = 0; c2 < 2; ++c2) {
            int c = 2 * bh + c2;
            const _Float16* rp = hb + (c * 16 + ln16) * HP;
            half8 Ah[4];
            #pragma unroll
            for (int kt = 0; kt < 4; ++kt)
                Ah[kt] = *(const half8*)(rp + kt * 32 + q * 8);
            f32x4 a0 = {0,0,0,0}, a1v = {0,0,0,0};
            #pragma unroll
            for (int kt = 0; kt < 4; ++kt) {
                a0  = MFMA(Ah[kt], Bw[kt][0], a0);
                a1v = MFMA(Ah[kt], Bw[kt][1], a1v);
            }
            // stored col[6:5] = dim[6:5] ^ batchrow[1:0] (=i); dim[6:5]=dg, dim[4]=nt
            #pragma unroll
            for (int i = 0; i < 4; ++i) {
                float v0 = a0[i] + b1rv[0];
                v0 = v0 > 0.0f ? v0 : 0.0f;
                a1s[(c * 16 + q * 4 + i) * HP + ((dg ^ i) << 5) + ln16] = (_Float16)v0;
                float v1 = a1v[i] + b1rv[1];
                v1 = v1 > 0.0f ? v1 : 0.0f;
                a1s[(c * 16 + q * 4 + i) * HP + ((dg ^ i) << 5) + 16 + ln16] = (_Float16)v1;
            }
        }
        __syncthreads();
        if (wave < 4) {   // phase 2: A=a1 (m=batch), B=w2f (n=out-dim) — unchanged
            const int sw = ln16 & 3;
            const _Float16* rp = a1s + (wave * 16 + ln16) * HP;
            f32x4 o = {0,0,0,0};
            #pragma unroll
            for (int kt = 0; kt < 4; ++kt) {
                half8 Aa = *(const half8*)(rp + ((kt ^ sw) << 5) + q * 8);
                half8 Bw2 = *(const half8*)&w2f[((kt * 4 + q) * 16 + ln16) * 8];
                o = MFMA(Aa, Bw2, o);
            }
            if (ln16 < 6) {
                #pragma unroll
                for (int i = 0; i < 4; ++i) {
                    int row = wave * 16 + q * 4 + i;
                    float v = o[i] + b2r;
                    out[(rowbase + row) * 180 + f * 6 + ln16] = v;
                    xdec[row * 8 + ln16] = (_Float16)v;   // next decoder x
                }
            }
        }
        __syncthreads();
    };

    int p = 0;
    #pragma unroll 1
    for (int t = 0; t < 50; ++t) { gru_step(p, t, true); p ^= 1; }
    #pragma unroll 1
    for (int f = 0; f < 30; ++f) {
        gru_step(p, f == 0 ? 49 : 0, f == 0);   // f=0: x = history[:,49]
        p ^= 1;
        head_step(f, p);
    }
}

extern "C" void kernel_launch(void* const* d_in, const int* in_sizes, int n_in,
                              void* d_out, int out_size, void* d_ws, size_t ws_size,
                              hipStream_t stream) {
    (void)in_sizes; (void)n_in; (void)d_ws; (void)ws_size; (void)out_size;
    traj_gru<<<dim3(16384 / ROWS), dim3(512), 0, stream>>>(
        (const float*)d_in[0], (const float*)d_in[1], (const float*)d_in[2],
        (const float*)d_in[3], (const float*)d_in[4], (const float*)d_in[5],
        (const float*)d_in[6], (const float*)d_in[7], (const float*)d_in[8],
        (float*)d_out);
}